// Round 4
// baseline (4813.809 us; speedup 1.0000x reference)
//
#include <hip/hip_runtime.h>
#include <math.h>

#define BATCH 512
#define TT    128
#define FF    64
#define UU    1024
#define ZZ    4096
#define OS    32
#define KTOT  1088
#define NCHW  17            // warmup K chunks of 64 (0 = x, 1..16 = h)
#define NCHD  16            // decode K chunks of 64 (h only, K=1024)
#define CROW  72            // A LDS row stride in f16 (64 + 8 pad = 144 B)
#define CBUF  (32 * CROW)   // 2304 f16 = 4608 B per A chunk buffer (BM=32)
#define NKBW  68            // warmup k16 blocks per n-tile (1088/16)
#define NKBD  64            // decode k16 blocks per n-tile (1024/16)

typedef _Float16 f16x8 __attribute__((ext_vector_type(8)));
typedef float f32x16 __attribute__((ext_vector_type(16)));
typedef float f32x8 __attribute__((ext_vector_type(8)));
typedef unsigned long long u64;

union F16Q { u64 q[2]; f16x8 v; };

__device__ __forceinline__ float sigf(float x) { return 1.0f / (1.0f + expf(-x)); }

#define REP16(M) M(0) M(1) M(2) M(3) M(4) M(5) M(6) M(7) \
                 M(8) M(9) M(10) M(11) M(12) M(13) M(14) M(15)

// ---------------------------------------------------------------------------
// wconv: [Wk;Wr] (1088x4096 fp32) -> f16 fragment-linear, gate-interleaved
// ---------------------------------------------------------------------------
__global__ __launch_bounds__(256) void wconv(
    const float* __restrict__ Wk, const float* __restrict__ Wr,
    _Float16* __restrict__ WT)
{
    __shared__ float T[32][129];
    const int k0 = blockIdx.x * 32;   // 34
    const int n0 = blockIdx.y * 128;  // 32
    const int u0 = n0 >> 2;
    const int t = threadIdx.x;
    #pragma unroll
    for (int i = 0; i < 16; ++i) {
        int idx = t + i * 256;
        int u = idx & 31, k = (idx >> 5) & 31, g = idx >> 10;
        int krow = k0 + k;
        int col = g * UU + u0 + u;
        float wv = (krow < FF) ? Wk[(size_t)krow * ZZ + col]
                               : Wr[(size_t)(krow - FF) * ZZ + col];
        T[k][u * 4 + g] = wv;
    }
    __syncthreads();
    #pragma unroll
    for (int i = 0; i < 16; ++i) {
        int idx = t + i * 256;
        int k = idx & 31, np = idx >> 5;
        int r = n0 + np, kk = k0 + k;
        size_t o = ((size_t)(r >> 5) * NKBW + (kk >> 4)) * 512
                 + (size_t)((((kk >> 3) & 1) * 32 + (r & 31)) * 8 + (kk & 7));
        WT[o] = (_Float16)T[k][np];
    }
}

// ---------------------------------------------------------------------------
// wfus: WT2 = Wr + Wd@Wk (1024x4096), fragment-linear f16 (NKBD blocks/n-tile)
// ---------------------------------------------------------------------------
__global__ __launch_bounds__(256) void wfus(
    const float* __restrict__ Wk, const float* __restrict__ Wr,
    const float* __restrict__ Wd, _Float16* __restrict__ WT2)
{
    __shared__ float Wkk[64][128];    // [f][np]
    __shared__ float Wdd[32][65];     // [k][f], padded
    const int k0 = blockIdx.x * 32;   // 32 (u-rows)
    const int n0 = blockIdx.y * 128;  // 32
    const int u0 = n0 >> 2;
    const int t = threadIdx.x;
    #pragma unroll
    for (int i = 0; i < 32; ++i) {
        int idx = t + i * 256;        // 8192 = 64 f x 128 np
        int f = idx >> 7, np = idx & 127;
        int col = (np & 3) * UU + u0 + (np >> 2);
        Wkk[f][np] = Wk[(size_t)f * ZZ + col];
    }
    #pragma unroll
    for (int i = 0; i < 8; ++i) {
        int idx = t + i * 256;        // 2048 = 32 k x 64 f
        int k = idx >> 6, f = idx & 63;
        Wdd[k][f] = Wd[(size_t)(k0 + k) * FF + f];
    }
    __syncthreads();
    #pragma unroll 1
    for (int i = 0; i < 16; ++i) {
        int idx = t + i * 256;
        int k = idx & 31, np = idx >> 5;
        int col = (np & 3) * UU + u0 + (np >> 2);
        float v = Wr[(size_t)(k0 + k) * ZZ + col];
        #pragma unroll
        for (int f = 0; f < 64; ++f) v += Wdd[k][f] * Wkk[f][np];
        int r = n0 + np, kk = k0 + k;
        size_t o = ((size_t)(r >> 5) * NKBD + (kk >> 4)) * 512
                 + (size_t)((((kk >> 3) & 1) * 32 + (r & 31)) * 8 + (kk & 7));
        WT2[o] = (_Float16)v;
    }
}

// bfus: b2 = b + bd@Wk  (4096)
__global__ __launch_bounds__(256) void bfus(
    const float* __restrict__ Wk, const float* __restrict__ b,
    const float* __restrict__ bd, float* __restrict__ b2)
{
    int col = blockIdx.x * 256 + threadIdx.x;
    float v = b[col];
    #pragma unroll 8
    for (int f = 0; f < 64; ++f) v += bd[f] * Wk[(size_t)f * ZZ + col];
    b2[col] = v;
}

// ---------------------------------------------------------------------------
// init: zero h0 (1MB) + flags (2KB)
// ---------------------------------------------------------------------------
__global__ __launch_bounds__(256) void init_k(
    uint4* __restrict__ h0, uint4* __restrict__ flz)
{
    const int b = blockIdx.x, t = threadIdx.x;
    if (b < 256) {
        h0[(size_t)b * 256 + t] = make_uint4(0u, 0u, 0u, 0u);
    } else {
        if (t < 128) flz[t] = make_uint4(0u, 0u, 0u, 0u);
    }
}

// ---------------------------------------------------------------------------
// One LSTM cell step for a 32x128 tile. ALL 16 h-chunks loaded upfront into
// registers via relaxed agent-scope (sc0 sc1, LLC-coherent) atomics — fully
// manually unrolled, literal indices only (no dynamic array indexing ->
// guaranteed registers, 16-deep latency cover). W direct VGPR 4-slot ring,
// 32x32x16 MFMA, C-frag -> z in LDS -> fused gates with c in registers.
// ---------------------------------------------------------------------------
template<int NCH, int HASX>
__device__ __forceinline__ void cell_step(
    const float* aAx, const _Float16* aAh, const _Float16* __restrict__ pW,
    _Float16* lds, float* z, const float bb[4], float creg[4],
    _Float16* hFo,
    int t, int lane, int nw, int r0, int u0, int wA, int fra)
{
    u64 sA[16][2];
    u64 xq[2];
    f32x8 xv;
    f32x16 acc;
    #pragma unroll
    for (int i = 0; i < 16; ++i) acc[i] = 0.f;
    f16x8 wf[4][4];

#define LOADW(ch)                                                              \
    if ((ch) < NCH) {                                                          \
        wf[(ch) & 3][0] = *(const f16x8*)(pW + ((ch) * 4 + 0) * 512);          \
        wf[(ch) & 3][1] = *(const f16x8*)(pW + ((ch) * 4 + 1) * 512);          \
        wf[(ch) & 3][2] = *(const f16x8*)(pW + ((ch) * 4 + 2) * 512);          \
        wf[(ch) & 3][3] = *(const f16x8*)(pW + ((ch) * 4 + 3) * 512);          \
    }
#define LOADH(k)                                                               \
    {                                                                          \
        const u64* p = (const u64*)(aAh + (k) * 64);                           \
        sA[k][0] = __hip_atomic_load(p, __ATOMIC_RELAXED,                      \
                                     __HIP_MEMORY_SCOPE_AGENT);               \
        sA[k][1] = __hip_atomic_load(p + 1, __ATOMIC_RELAXED,                  \
                                     __HIP_MEMORY_SCOPE_AGENT);               \
    }
#define WRITEA(ch)                                                             \
    if ((ch) < NCH) {                                                          \
        u64* q = (u64*)(lds + ((ch) & 1) * CBUF + wA);                         \
        if (HASX && (ch) == 0) {                                               \
            q[0] = xq[0]; q[1] = xq[1];                                        \
        } else {                                                               \
            constexpr int KI = ((ch) >= HASX) ? (ch) - HASX : 0;               \
            q[0] = sA[KI][0]; q[1] = sA[KI][1];                                \
        }                                                                      \
    }
#define CHUNK(ch)                                                              \
    if ((ch) < NCH) {                                                          \
        LOADW((ch) + 3)                                                        \
        __builtin_amdgcn_s_waitcnt(0xC07F);   /* lgkmcnt(0) only */            \
        __builtin_amdgcn_s_barrier();                                          \
        WRITEA((ch) + 1)                                                       \
        const _Float16* bp = lds + ((ch) & 1) * CBUF;                          \
        f16x8 af;                                                              \
        af = *(const f16x8*)(bp + fra);                                        \
        acc = __builtin_amdgcn_mfma_f32_32x32x16_f16(af, wf[(ch) & 3][0], acc, 0, 0, 0); \
        af = *(const f16x8*)(bp + fra + 16);                                   \
        acc = __builtin_amdgcn_mfma_f32_32x32x16_f16(af, wf[(ch) & 3][1], acc, 0, 0, 0); \
        af = *(const f16x8*)(bp + fra + 32);                                   \
        acc = __builtin_amdgcn_mfma_f32_32x32x16_f16(af, wf[(ch) & 3][2], acc, 0, 0, 0); \
        af = *(const f16x8*)(bp + fra + 48);                                   \
        acc = __builtin_amdgcn_mfma_f32_32x32x16_f16(af, wf[(ch) & 3][3], acc, 0, 0, 0); \
    }

    LOADW(0) LOADW(1) LOADW(2)
    if (HASX) xv = *(const f32x8*)aAx;       // 2x dwordx4, plain cached
    REP16(LOADH)                             // 16 chunks in flight (32 x 8B)
    if (HASX) {                              // convert x fp32 -> f16 in regs
        F16Q q;
        #pragma unroll
        for (int j = 0; j < 8; ++j) q.v[j] = (_Float16)xv[j];
        xq[0] = q.q[0]; xq[1] = q.q[1];
    }
    WRITEA(0)
    REP16(CHUNK)
    CHUNK(16)

#undef LOADW
#undef LOADH
#undef WRITEA
#undef CHUNK

    __syncthreads();
    {   // C-frag (col=lane&31, row=(r&3)+8*(r>>2)+4*(lane>>5)) -> z[m][g][u]
        const int l31 = lane & 31;
        const int nloc = nw * 32 + l31;
        const int gs = (nloc & 3) * 33 + (nloc >> 2);
        const int rbase = 4 * (lane >> 5);
        #pragma unroll
        for (int r = 0; r < 16; ++r) {
            int m = rbase + (r & 3) + 8 * (r >> 2);
            z[m * 132 + gs] = acc[r];
        }
    }
    __syncthreads();
    {   // gates: thread (u = t&31), 4 m-rows; c in registers, bias hoisted
        const int ul = t & 31;
        #pragma unroll
        for (int rep = 0; rep < 4; ++rep) {
            int m = (t >> 5) * 4 + rep;
            float zi = z[m * 132 + ul] + bb[0];
            float zf = z[m * 132 + 33 + ul] + bb[1];
            float zg = z[m * 132 + 66 + ul] + bb[2];
            float zo = z[m * 132 + 99 + ul] + bb[3];
            float cn = sigf(zf) * creg[rep] + sigf(zi) * tanhf(zg);
            creg[rep] = cn;
            unsigned hv = (unsigned)__builtin_bit_cast(
                unsigned short, (_Float16)(sigf(zo) * tanhf(cn)));
            unsigned pv = (unsigned)__shfl_xor((int)hv, 1, 64);
            if ((ul & 1) == 0) {
                size_t idx = (size_t)(r0 + m) * UU + (u0 + ul);
                __hip_atomic_store((unsigned*)(hFo + idx), hv | (pv << 16),
                                   __ATOMIC_RELAXED, __HIP_MEMORY_SCOPE_AGENT);
            }
        }
    }
}

// ---------------------------------------------------------------------------
// dense_row: one output row per block. out[row][sidx][:] = h[row]@Wd + bd.
// h row (2KB) staged to LDS via agent-scope loads; 256 thr: ks=t>>6 k-quarter,
// f=t&63 output col; 4-way smem reduce. ~0.5us, uniform across the group.
// ---------------------------------------------------------------------------
__device__ __forceinline__ void dense_row(
    const _Float16* hrow, const float* __restrict__ Wd,
    const float* __restrict__ bd, float* __restrict__ orow,
    char* smem, int t)
{
    _Float16* hl = (_Float16*)smem;            // 1024 f16 = 2KB
    float* red = (float*)(smem + 4096);        // 4 x 64 f32
    __syncthreads();                           // smem handoff (z -> hl)
    if (t < 128) {
        const u64* p = (const u64*)(hrow + t * 8);
        u64 a0 = __hip_atomic_load(p, __ATOMIC_RELAXED, __HIP_MEMORY_SCOPE_AGENT);
        u64 a1 = __hip_atomic_load(p + 1, __ATOMIC_RELAXED, __HIP_MEMORY_SCOPE_AGENT);
        u64* q = (u64*)hl + t * 2;
        q[0] = a0; q[1] = a1;
    }
    __syncthreads();
    const int f = t & 63, ks = t >> 6;
    const float* wp = Wd + (size_t)(ks * 256) * FF + f;
    const _Float16* hk = hl + ks * 256;
    float s = 0.f;
    #pragma unroll 2
    for (int v = 0; v < 32; ++v) {
        f16x8 a = *(const f16x8*)(hk + v * 8);
        #pragma unroll
        for (int j = 0; j < 8; ++j) s += (float)a[j] * wp[(size_t)(v * 8 + j) * FF];
    }
    red[ks * 64 + f] = s;
    __syncthreads();
    if (t < 64) {
        orow[t] = bd[t] + red[t] + red[64 + t] + red[128 + t] + red[192 + t];
    }
}

// ---------------------------------------------------------------------------
// Persistent kernel: 512 blocks (2/CU, exactly co-resident). Per-rtile
// (32-block) FLAG barrier: each block stores its step to its own slot (one
// 128B line per group), every wave polls the line with __all — no atomic
// RMW serialization, no release/acquire cache maintenance anywhere.
// ---------------------------------------------------------------------------
__global__ __launch_bounds__(256, 2) void lstm_persist(
    const float* __restrict__ inputs,
    _Float16* hF0, _Float16* hF1,
    const _Float16* __restrict__ WT, const float* __restrict__ bias,
    const _Float16* __restrict__ WT2, const float* __restrict__ b2,
    const float* __restrict__ Wd, const float* __restrict__ bd,
    float* __restrict__ out, unsigned* fl)
{
    __shared__ __align__(16) char smem[32 * 132 * 4];   // 16896 B
    _Float16* lds = (_Float16*)smem;
    float* z = (float*)smem;

    const int t = threadIdx.x;
    const int lane = t & 63;
    const int nw = t >> 6;
    const int bid = blockIdx.x;
    const int panel = bid & 31, rtile = bid >> 5;   // same-panel blocks share an XCD (bid%8)
    const int r0 = rtile * 32, u0 = panel * 32;
    const int srow = t >> 3, sseg = t & 7;
    const int wA = srow * CROW + sseg * 8;
    const int fra = (lane & 31) * CROW + (lane >> 5) * 8;

    // x: fp32 inputs [B][T][F]; per-step slab offset = step*FF
    const float* aAxBase = inputs + (size_t)(r0 + srow) * (TT * FF) + sseg * 8;
    const size_t aoh = (size_t)(r0 + srow) * UU + sseg * 8;
    const _Float16* pW  = WT  + ((size_t)(panel * 4 + nw) * NKBW) * 512 + lane * 8;
    const _Float16* pW2 = WT2 + ((size_t)(panel * 4 + nw) * NKBD) * 512 + lane * 8;

    // hoisted per-thread state: biases + register-resident c
    const int uu = u0 + (t & 31);
    float bw[4], bdc[4], creg[4] = {0.f, 0.f, 0.f, 0.f};
    bw[0] = bias[uu];          bw[1] = bias[UU + uu];
    bw[2] = bias[2 * UU + uu]; bw[3] = bias[3 * UU + uu];
    bdc[0] = b2[uu];           bdc[1] = b2[UU + uu];
    bdc[2] = b2[2 * UU + uu];  bdc[3] = b2[3 * UU + uu];

    unsigned* slot = fl + (rtile << 5) + (t & 31);   // this lane's polled slot
    unsigned* myslot = fl + (rtile << 5) + panel;    // this block's own slot
    _Float16 *hc = hF0, *hn = hF1;

#define GROUP_SYNC(STEPV)                                                      \
    {                                                                          \
        __syncthreads();   /* drains vmcnt(0): h stores visible at LLC */      \
        if (t == 0)                                                            \
            __hip_atomic_store(myslot, (unsigned)(STEPV), __ATOMIC_RELAXED,    \
                               __HIP_MEMORY_SCOPE_AGENT);                      \
        while (!__all((int)(__hip_atomic_load(slot, __ATOMIC_RELAXED,          \
                                              __HIP_MEMORY_SCOPE_AGENT)       \
                            >= (unsigned)(STEPV))))                            \
            __builtin_amdgcn_s_sleep(2);                                       \
    }

    // ---- warmup: 128 steps ----
    #pragma unroll 1
    for (int step = 0; step < TT; ++step) {
        cell_step<NCHW, 1>(aAxBase + (size_t)step * FF, hc + aoh, pW,
                           lds, z, bw, creg, hn, t, lane, nw, r0, u0, wA, fra);
        GROUP_SYNC(step + 1);
        _Float16* tp = hc; hc = hn; hn = tp;
    }

    // ---- decode: 31 steps; every block does one dense row of out[s-1] ----
    #pragma unroll 1
    for (int s = 1; s < OS; ++s) {
        cell_step<NCHD, 0>(nullptr, hc + aoh, pW2,
                           lds, z, bdc, creg, hn, t, lane, nw, r0, u0, wA, fra);
        dense_row(hc + (size_t)(r0 + panel) * UU, Wd, bd,
                  out + (size_t)(r0 + panel) * (OS * FF) + (size_t)(s - 1) * FF,
                  smem, t);
        GROUP_SYNC(TT + s);
        _Float16* tp = hc; hc = hn; hn = tp;
    }

    // final dense on h_31 (group-synced by last iteration's barrier)
    dense_row(hc + (size_t)(r0 + panel) * UU, Wd, bd,
              out + (size_t)(r0 + panel) * (OS * FF) + (size_t)(OS - 1) * FF,
              smem, t);
#undef GROUP_SYNC
}

extern "C" void kernel_launch(void* const* d_in, const int* in_sizes, int n_in,
                              void* d_out, int out_size, void* d_ws, size_t ws_size,
                              hipStream_t stream) {
    const float* inputs = (const float*)d_in[0];
    const float* Wk     = (const float*)d_in[1];
    const float* Wr     = (const float*)d_in[2];
    const float* bias   = (const float*)d_in[3];
    const float* Wd     = (const float*)d_in[4];
    const float* bd     = (const float*)d_in[5];
    float* out = (float*)d_out;

    char* ws = (char*)d_ws;
    _Float16* hF0 = (_Float16*)(ws);                  // 1 MB (zeroed)
    _Float16* hF1 = (_Float16*)(ws + 1048576);        // 1 MB
    _Float16* WT  = (_Float16*)(ws + 2097152);        // 8,912,896 (warm frag)
    _Float16* WT2 = (_Float16*)(ws + 11010048);       // 8,388,608 (fused frag)
    float*    b2  = (float*)(ws + 19398656);          // 16 KB
    unsigned* fl  = (unsigned*)(ws + 19415040);       // 2 KB flags (zeroed)

    wconv<<<dim3(34, 32), 256, 0, stream>>>(Wk, Wr, WT);
    wfus<<<dim3(32, 32), 256, 0, stream>>>(Wk, Wr, Wd, WT2);
    bfus<<<16, 256, 0, stream>>>(Wk, bias, bd, b2);
    init_k<<<257, 256, 0, stream>>>((uint4*)hF0, (uint4*)fl);

    // persistent: 512 blocks x 256 thr = 2 blocks/CU on 256 CUs (exact fit)
    lstm_persist<<<512, 256, 0, stream>>>(inputs, hF0, hF1,
                                          WT, bias, WT2, b2, Wd, bd, out, fl);
}